// Round 5
// baseline (347.408 us; speedup 1.0000x reference)
//
#include <hip/hip_runtime.h>
#include <hip/hip_bf16.h>
#include <stdint.h>

// Problem constants (fixed by the reference)
#define M_ROWS 4096   // B
#define N_COLS 8192   // N
#define KDIM   512    // D

// GEMM: 256x256 tile, 8 waves (2M x 4N), BK=32 K-tiles, 4-deep LDS ring
#define BM 256
#define BN 256
#define BKT 32
#define NKT 16        // 512 / 32

typedef __attribute__((ext_vector_type(8))) __bf16 bf16x8;
typedef __attribute__((ext_vector_type(4))) float  f32x4;
typedef __attribute__((ext_vector_type(4))) int    i32x4;

// compiler-only fence + hw barrier (raw: no implicit vmcnt(0) drain)
#define BAR() do { asm volatile("" ::: "memory"); \
                   __builtin_amdgcn_s_barrier();  \
                   asm volatile("" ::: "memory"); } while (0)

// ---------- fp32 -> bf16 (RNE) ----------
__device__ __forceinline__ unsigned short f2bf(float f) {
  union { float f; uint32_t u; } v; v.f = f;
  uint32_t u = v.u;
  u += 0x7fffu + ((u >> 16) & 1u);
  return (unsigned short)(u >> 16);
}

// ---------- kernel 1: fp32 -> bf16 conversion only ----------
__global__ __launch_bounds__(256) void cvt_kernel(const float* __restrict__ A,
                                                  const float* __restrict__ S,
                                                  unsigned short* __restrict__ Abf,
                                                  unsigned short* __restrict__ Sbf) {
  int g = blockIdx.x * 256 + threadIdx.x;
  #pragma unroll
  for (int it = 0; it < 4; ++it) {
    int idx = g + it * 393216;
    float4 v; ushort4 o;
    if (idx < 524288) {
      v = reinterpret_cast<const float4*>(A)[idx];
      o.x = f2bf(v.x); o.y = f2bf(v.y); o.z = f2bf(v.z); o.w = f2bf(v.w);
      reinterpret_cast<ushort4*>(Abf)[idx] = o;
    } else {
      int q = idx - 524288;
      v = reinterpret_cast<const float4*>(S)[q];
      o.x = f2bf(v.x); o.y = f2bf(v.y); o.z = f2bf(v.z); o.w = f2bf(v.w);
      reinterpret_cast<ushort4*>(Sbf)[q] = o;
    }
  }
}

// ---------- GEMM helpers (verified R2 core, untouched) ----------
__device__ __forceinline__ int swz_x(int r) { return (r & 3) ^ ((r >> 2) & 3); }

__device__ __forceinline__ bf16x8 lds_frag(const unsigned short* chunk, int r, int lk) {
  int g = lk ^ swz_x(r);
  return *reinterpret_cast<const bf16x8*>(chunk + r * 32 + g * 8);
}

__device__ __forceinline__ void stage_chunk(const unsigned short* __restrict__ srcBase,
                                            int tt, unsigned short* chunk,
                                            int w, int l) {
  #pragma unroll
  for (int jj = 0; jj < 2; ++jj) {
    int r = jj * 128 + w * 16 + (l >> 2);
    int g = (l & 3) ^ swz_x(r);
    const unsigned short* src = srcBase + (size_t)r * KDIM + tt * BKT + g * 8;
    __builtin_amdgcn_global_load_lds(
        (const __attribute__((address_space(1))) void*)src,
        (__attribute__((address_space(3))) void*)(chunk + jj * 4096 + w * 512),
        16, 0, 0);
  }
}

// One K-tile, R2 structure/ledger. 4 barriers per tile.
// vmcnt ledger: end of tile T in-flight = A(T+2),B(T+2),A(T+3),B(T+3) = 8
// -> staging(T+1) landed after vmcnt(8). T=13: 4. T=14: 0. T=15: none.
template<int T>
__device__ __forceinline__ void do_tile(unsigned short (*lds)[2][BM * BKT],
                                        const unsigned short* __restrict__ Abase,
                                        const unsigned short* __restrict__ Sbase,
                                        f32x4 (&acc)[8][4],
                                        int wr, int wc, int lr, int lk,
                                        int w, int lane) {
  constexpr bool STAGE = (T <= NKT - 4);
  const unsigned short* cA = lds[T & 3][0];
  const unsigned short* cB = lds[T & 3][1];

  bf16x8 bfr[4], afr[4];
  #pragma unroll
  for (int n = 0; n < 4; ++n) bfr[n] = lds_frag(cB, wc * 64 + n * 16 + lr, lk);
  #pragma unroll
  for (int m = 0; m < 4; ++m) afr[m] = lds_frag(cA, wr * 128 + m * 16 + lr, lk);
  if constexpr (STAGE) stage_chunk(Abase, T + 3, lds[(T + 3) & 3][0], w, lane);
  BAR();
  __builtin_amdgcn_s_setprio(1);
  #pragma unroll
  for (int m = 0; m < 4; ++m)
    #pragma unroll
    for (int n = 0; n < 4; ++n)
      acc[m][n] = __builtin_amdgcn_mfma_f32_16x16x32_bf16(afr[m], bfr[n],
                                                          acc[m][n], 0, 0, 0);
  __builtin_amdgcn_s_setprio(0);
  BAR();
  #pragma unroll
  for (int m = 0; m < 4; ++m) afr[m] = lds_frag(cA, wr * 128 + (m + 4) * 16 + lr, lk);
  if constexpr (STAGE) stage_chunk(Sbase, T + 3, lds[(T + 3) & 3][1], w, lane);
  BAR();
  __builtin_amdgcn_s_setprio(1);
  #pragma unroll
  for (int m = 0; m < 4; ++m)
    #pragma unroll
    for (int n = 0; n < 4; ++n)
      acc[m + 4][n] = __builtin_amdgcn_mfma_f32_16x16x32_bf16(afr[m], bfr[n],
                                                              acc[m + 4][n], 0, 0, 0);
  __builtin_amdgcn_s_setprio(0);
  if constexpr (T <= 12)      asm volatile("s_waitcnt vmcnt(8)" ::: "memory");
  else if constexpr (T == 13) asm volatile("s_waitcnt vmcnt(4)" ::: "memory");
  else if constexpr (T == 14) asm volatile("s_waitcnt vmcnt(0)" ::: "memory");
  BAR();
}

// ---------- kernel 2: GEMM (waves 0-7) + one-hot scanner (wave 8) ----------
// 576 threads = 9 waves. Scanner has its OWN vmcnt domain (per-wave counters),
// so its HBM-latency loads never couple into the GEMM staging pipeline (R4
// failure mode). Both paths execute exactly 66 barriers.
__global__ __launch_bounds__(576, 2) void gemm_scan_kernel(
    const unsigned short* __restrict__ Abf,
    const unsigned short* __restrict__ Sbf,
    const int* __restrict__ onehot,
    int* __restrict__ pos_idx,
    float* __restrict__ rsum, float* __restrict__ rmin) {
  __shared__ alignas(16) unsigned short lds[4][2][BM * BKT];  // 128 KB ring

  const int tid  = threadIdx.x;
  const int bx   = blockIdx.x;          // 512 blocks: 16 row-panels x 32 col
  const int w    = tid >> 6;
  const int lane = tid & 63;

  if (w < 8) {
    // ================= GEMM path (identical to verified R2 core) ==========
    const int wr = w >> 2, wc = w & 3;
    const int lr = lane & 15, lk = lane >> 4;
    const int rp = bx & 15, cp = bx >> 4;
    const int rowBase = rp * BM;

    const unsigned short* Abase = Abf + (size_t)rowBase * KDIM;
    const unsigned short* Sbase = Sbf + (size_t)cp * BN * KDIM;

    f32x4 acc[8][4];
    #pragma unroll
    for (int m = 0; m < 8; ++m)
      #pragma unroll
      for (int n = 0; n < 4; ++n)
        acc[m][n] = (f32x4){0.f, 0.f, 0.f, 0.f};

    #pragma unroll
    for (int tt = 0; tt < 3; ++tt) {
      stage_chunk(Abase, tt, lds[tt][0], w, lane);
      stage_chunk(Sbase, tt, lds[tt][1], w, lane);
    }
    asm volatile("s_waitcnt vmcnt(8)" ::: "memory");
    BAR();                                                   // barrier 1

    do_tile<0>(lds, Abase, Sbase, acc, wr, wc, lr, lk, w, lane);
    do_tile<1>(lds, Abase, Sbase, acc, wr, wc, lr, lk, w, lane);
    do_tile<2>(lds, Abase, Sbase, acc, wr, wc, lr, lk, w, lane);
    do_tile<3>(lds, Abase, Sbase, acc, wr, wc, lr, lk, w, lane);
    do_tile<4>(lds, Abase, Sbase, acc, wr, wc, lr, lk, w, lane);
    do_tile<5>(lds, Abase, Sbase, acc, wr, wc, lr, lk, w, lane);
    do_tile<6>(lds, Abase, Sbase, acc, wr, wc, lr, lk, w, lane);
    do_tile<7>(lds, Abase, Sbase, acc, wr, wc, lr, lk, w, lane);
    do_tile<8>(lds, Abase, Sbase, acc, wr, wc, lr, lk, w, lane);
    do_tile<9>(lds, Abase, Sbase, acc, wr, wc, lr, lk, w, lane);
    do_tile<10>(lds, Abase, Sbase, acc, wr, wc, lr, lk, w, lane);
    do_tile<11>(lds, Abase, Sbase, acc, wr, wc, lr, lk, w, lane);
    do_tile<12>(lds, Abase, Sbase, acc, wr, wc, lr, lk, w, lane);
    do_tile<13>(lds, Abase, Sbase, acc, wr, wc, lr, lk, w, lane);
    do_tile<14>(lds, Abase, Sbase, acc, wr, wc, lr, lk, w, lane);
    do_tile<15>(lds, Abase, Sbase, acc, wr, wc, lr, lk, w, lane);
    // barriers so far: 1 + 16*4 = 65

    // ---- epilogue: per-row (sum, min) over this block's 256 cols ----
    // C/D layout: col = wc*64 + n*16 + (lane&15); row = wr*128+m*16+lk*4+r.
    float* eps = (float*)&lds[0][0][0];     // [256 rows][4 cls][4 wc]
    float* epm = eps + 4096;
    #pragma unroll
    for (int m = 0; m < 8; ++m)
      #pragma unroll
      for (int r = 0; r < 4; ++r) {
        float s_ = (acc[m][0][r] + acc[m][1][r]) + (acc[m][2][r] + acc[m][3][r]);
        float n_ = fminf(fminf(acc[m][0][r], acc[m][1][r]),
                         fminf(acc[m][2][r], acc[m][3][r]));
        s_ += __shfl_xor(s_, 4, 64);
        n_ = fminf(n_, __shfl_xor(n_, 4, 64));
        s_ += __shfl_xor(s_, 8, 64);
        n_ = fminf(n_, __shfl_xor(n_, 8, 64));
        if ((lane & 12) == 0) {
          int row = wr * 128 + m * 16 + lk * 4 + r;
          int cls = lane & 3;
          eps[(row * 4 + cls) * 4 + wc] = s_;
          epm[(row * 4 + cls) * 4 + wc] = n_;
        }
      }
    __syncthreads();                                         // barrier 66
    #pragma unroll
    for (int item = tid; item < 1024; item += 512) {
      int row = item >> 2, cls = item & 3;
      float s0 = (eps[item * 4 + 0] + eps[item * 4 + 1]) +
                 (eps[item * 4 + 2] + eps[item * 4 + 3]);
      float m0 = fminf(fminf(epm[item * 4 + 0], epm[item * 4 + 1]),
                       fminf(epm[item * 4 + 2], epm[item * 4 + 3]));
      size_t gi = (size_t)(rowBase + row) * 128 + cp * 4 + cls;
      rsum[gi] = s0;
      rmin[gi] = m0;
    }
  } else {
    // ================= scanner wave (wave 8, lanes sl=0..63) ==============
    // Scans one-hot rows bx*8 .. bx*8+7; slice t = row t>>1, half t&1.
    // Own vmcnt domain; only obligation: 66 barrier arrivals.
    const int sl = lane;
    const i32x4* base = reinterpret_cast<const i32x4*>(onehot + (size_t)bx * 8 * N_COLS);
    BAR();                                                   // barrier 1
    #pragma unroll 1
    for (int t = 0; t < 16; ++t) {
      const int rr = t >> 1, half = t & 1;
      const i32x4* rowp = base + rr * 2048 + half * 1024;
      #pragma unroll
      for (int i = 0; i < 16; ++i) {
        i32x4 v = __builtin_nontemporal_load(&rowp[i * 64 + sl]);
        if (v[0] | v[1] | v[2] | v[3]) {
          int idx4 = half * 1024 + i * 64 + sl;
          int sub = v[0] ? 0 : (v[1] ? 1 : (v[2] ? 2 : 3));
          pos_idx[bx * 8 + rr] = idx4 * 4 + sub;   // one nonzero per row
        }
      }
      BAR(); BAR(); BAR(); BAR();                            // 4 per tile
    }
    __syncthreads();                                         // barrier 66
  }
}

// ---------- kernel 3: per-row loss via the no-clip identity ----------
// rowLoss = (R - p) - (N-1)(p-1) when min_n s >= p-1; guarded exact fp32
// slow path otherwise (never triggers for normalized random data).
__global__ __launch_bounds__(256) void fin1_kernel(
    const float* __restrict__ A, const float* __restrict__ Sm,
    const int* __restrict__ pos_idx,
    const float* __restrict__ rsum, const float* __restrict__ rmin,
    float* __restrict__ rowLoss) {
  const int w = threadIdx.x >> 6, lane = threadIdx.x & 63;
  #pragma unroll
  for (int i = 0; i < 2; ++i) {
    int row = blockIdx.x * 8 + w * 2 + i;
    int j = pos_idx[row];
    const float4* a4 = reinterpret_cast<const float4*>(A + (size_t)row * KDIM);
    const float4* s4 = reinterpret_cast<const float4*>(Sm + (size_t)j * KDIM);
    float4 x0 = a4[lane * 2], x1 = a4[lane * 2 + 1];
    float4 y0 = s4[lane * 2], y1 = s4[lane * 2 + 1];
    float dp = x0.x * y0.x + x0.y * y0.y + x0.z * y0.z + x0.w * y0.w
             + x1.x * y1.x + x1.y * y1.y + x1.z * y1.z + x1.w * y1.w;
    float rs = rsum[(size_t)row * 128 + lane] + rsum[(size_t)row * 128 + 64 + lane];
    float rm = fminf(rmin[(size_t)row * 128 + lane],
                     rmin[(size_t)row * 128 + 64 + lane]);
    #pragma unroll
    for (int off = 32; off > 0; off >>= 1) {
      dp += __shfl_down(dp, off, 64);
      rs += __shfl_down(rs, off, 64);
      rm = fminf(rm, __shfl_down(rm, off, 64));
    }
    float p  = __shfl(dp, 0, 64);
    float R  = __shfl(rs, 0, 64);
    float mn = __shfl(rm, 0, 64);
    float loss;
    if (mn >= p - 1.0f) {
      loss = (R - p) - (float)(N_COLS - 1) * (p - 1.0f);
    } else {
      float accv = 0.f;
      const float* arow = A + (size_t)row * KDIM;
      for (int n = lane; n < N_COLS; n += 64) {
        const float* srow = Sm + (size_t)n * KDIM;
        float d = 0.f;
        for (int k = 0; k < KDIM; ++k) d += arow[k] * srow[k];
        float h = fmaxf(d - p + 1.0f, 0.0f);
        accv += (n == j) ? 0.f : h;
      }
      #pragma unroll
      for (int off = 32; off > 0; off >>= 1) accv += __shfl_down(accv, off, 64);
      loss = __shfl(accv, 0, 64);
    }
    if (lane == 0) rowLoss[row] = loss;
  }
}

// ---------- kernel 4: deterministic final scalar ----------
__global__ __launch_bounds__(256) void fin2_kernel(const float* __restrict__ rowLoss,
                                                   float* __restrict__ out) {
  __shared__ double sd[256];
  double s = 0.0;
  for (int i = threadIdx.x; i < M_ROWS; i += 256) s += (double)rowLoss[i];
  sd[threadIdx.x] = s;
  __syncthreads();
  for (int st = 128; st > 0; st >>= 1) {
    if (threadIdx.x < st) sd[threadIdx.x] += sd[threadIdx.x + st];
    __syncthreads();
  }
  if (threadIdx.x == 0)
    *out = (float)(sd[0] / ((double)M_ROWS * (double)(N_COLS - 1)));
}

extern "C" void kernel_launch(void* const* d_in, const int* in_sizes, int n_in,
                              void* d_out, int out_size, void* d_ws, size_t ws_size,
                              hipStream_t stream) {
  const float* A  = (const float*)d_in[0];   // anchor [4096,512] f32
  const float* S  = (const float*)d_in[1];   // sample [8192,512] f32
  const int*   oh = (const int*)d_in[2];     // one-hot [4096,8192] int
  float* out = (float*)d_out;

  // workspace (~13.1 MB): pos | rsum | rmin | rowLoss | Abf | Sbf
  char* ws = (char*)d_ws;
  int*   pos_idx  = (int*)ws;                               // 16 KB
  float* rsum     = (float*)(ws + 16384);                   // 2 MB
  float* rmin     = (float*)(ws + 16384 + 2097152);         // 2 MB
  float* rowLoss  = (float*)(ws + 16384 + 4194304);         // 16 KB
  unsigned short* Abf = (unsigned short*)(ws + 16384 + 4194304 + 16384);  // 4 MB
  unsigned short* Sbf = Abf + (size_t)M_ROWS * KDIM;        // 8 MB

  cvt_kernel<<<1536, 256, 0, stream>>>(A, S, Abf, Sbf);
  gemm_scan_kernel<<<512, 576, 0, stream>>>(Abf, Sbf, oh, pos_idx, rsum, rmin);
  fin1_kernel<<<512, 256, 0, stream>>>(A, S, pos_idx, rsum, rmin, rowLoss);
  fin2_kernel<<<1, 256, 0, stream>>>(rowLoss, out);
}